// Round 16
// baseline (584.899 us; speedup 1.0000x reference)
//
#include <hip/hip_runtime.h>

typedef __attribute__((ext_vector_type(8))) short s16x8;
typedef __attribute__((ext_vector_type(4))) float f32x4;
typedef __attribute__((ext_vector_type(4))) unsigned short u16x4;

#define T_  2048
#define C_  1024
#define D_  64

__device__ __forceinline__ unsigned short f2bf(float f){
  union { float fv; unsigned int u; } v; v.fv = f;
  unsigned int r = v.u + 0x7FFFu + ((v.u >> 16) & 1u);
  return (unsigned short)(r >> 16);
}

__device__ __forceinline__ float exp2_asm(float x){
  float r; asm("v_exp_f32 %0, %1" : "=v"(r) : "v"(x)); return r;
}
__device__ __forceinline__ unsigned int cvtpk(float lo, float hi){
  unsigned int r; asm("v_cvt_pk_bf16_f32 %0, %1, %2" : "=v"(r) : "v"(lo), "v"(hi)); return r;
}

__device__ __forceinline__ void gload_lds16(const void* g, void* l){
  __builtin_amdgcn_global_load_lds(
      (const __attribute__((address_space(1))) unsigned int*)g,
      (__attribute__((address_space(3))) unsigned int*)l, 16, 0, 0);
}

// ---------------- fused fp32 -> bf16 convert (x, W_attn, W_proj in one launch) ----------------
__global__ __launch_bounds__(256) void cvt3_kernel(
    const float* __restrict__ x,  unsigned short* __restrict__ xb,
    const float* __restrict__ wa, unsigned short* __restrict__ wab,
    const float* __restrict__ wp, unsigned short* __restrict__ wpb){
  const int b = blockIdx.x;
  const float* s; unsigned short* d; size_t base;
  if (b < 4096)      { s = x;  d = xb;  base = (size_t)b * 2048u; }
  else if (b < 5632) { s = wa; d = wab; base = (size_t)(b - 4096) * 2048u; }
  else               { s = wp; d = wpb; base = (size_t)(b - 5632) * 2048u; }
  const size_t i = base + (size_t)threadIdx.x * 8u;
  f32x4 a = *(const f32x4*)(s + i);
  f32x4 c = *(const f32x4*)(s + i + 4);
  s16x8 o;
  #pragma unroll
  for (int j = 0; j < 4; ++j){ o[j] = (short)f2bf(a[j]); o[4+j] = (short)f2bf(c[j]); }
  *(s16x8*)(d + i) = o;
}

// ---------------- QKV GEMM 256x128, BK=32: tail-free grid (768 = 3/CU exact) ----------------
// R15 post-mortem: blocks are latency-limited at constant speed -> 6/CU at
// 4-resident = 1.5 rounds with a half-residency tail (25% idle).  Retile to
// 256x128 (512 thr, 8 waves, wave-tile 64x64 -- per-wave iteration body
// identical: 16 MFMA + 8 ds_read_b128), LDS 48KB -> EXACTLY 3 blocks/CU,
// 768 blocks = one residency round, zero tail, 24 waves/CU.
// Counted-vmcnt discipline kept: head vmcnt(3) (tile t landed, t+1 in
// flight), stage(t+2) at tail.  Same 0-conflict 64B-row swizzle + lean epilogue.
__global__ __launch_bounds__(512, 6) void gemm_qkv(
    const unsigned short* __restrict__ A, const unsigned short* __restrict__ Bw,
    const float* __restrict__ bias, int M, int N, int K, int nbx,
    unsigned short* __restrict__ q_ws, unsigned short* __restrict__ k_ws,
    unsigned short* __restrict__ vT_ws)
{
  __shared__ unsigned short Asm[2][256*32];   // 16 KB x2
  __shared__ unsigned short Bsm[2][128*32];   //  8 KB x2  (48 KB total -> 3 blocks/CU)
  const int tid = threadIdx.x;
  const int lane = tid & 63, wid = tid >> 6;
  const int g = lane >> 4, lr = lane & 15;
  const int wm = wid >> 1, wn = wid & 1;      // 4M x 2N, wave-tile 64x64
  const int nwg = (int)gridDim.x;
  const int cpx = nwg >> 3;
  const int orig = (int)blockIdx.x;
  const int wgid = (orig & 7) * cpx + (orig >> 3);   // XCD-chunked (nwg % 8 == 0)
  const int bx = wgid % nbx, by = wgid / nbx;
  const int m0 = by * 256, n0 = bx * 128;

  f32x4 acc[4][4];
  #pragma unroll
  for (int i = 0; i < 4; ++i)
    #pragma unroll
    for (int j = 0; j < 4; ++j) acc[i][j] = (f32x4){0.f,0.f,0.f,0.f};

  // stage one BK=32 tile: A 1024 chunks + B 512 chunks = 3 loads/thread
  auto stage = [&](int kt, int buf){
    #pragma unroll
    for (int j = 0; j < 2; ++j){
      const int c = j*512 + tid;              // A: 1024 chunks = 256 rows x 4
      const int row = c >> 2;
      const int srcq = ((c & 3) - (row >> 1)) & 3;
      gload_lds16((const char*)A + ((size_t)(m0+row)*K)*2 + (size_t)kt*64 + srcq*16,
                  (char*)&Asm[buf][0] + (size_t)c*16);
    }
    {
      const int c = tid;                      // B: 512 chunks = 128 rows x 4
      const int row = c >> 2;
      const int srcq = ((c & 3) - (row >> 1)) & 3;
      gload_lds16((const char*)Bw + ((size_t)(n0+row)*K)*2 + (size_t)kt*64 + srcq*16,
                  (char*)&Bsm[buf][0] + (size_t)c*16);
    }
  };

  const int nk = K >> 5;                      // 32 K-tiles
  stage(0, 0);
  stage(1, 1);                                // 6 outstanding

  for (int t = 0; t < nk; ++t){
    const int cur = t & 1;
    if (t < nk - 1) asm volatile("s_waitcnt vmcnt(3)" ::: "memory");  // tile t landed
    else            asm volatile("s_waitcnt vmcnt(0)" ::: "memory");
    asm volatile("s_barrier" ::: "memory");

    const char* At = (const char*)&Asm[cur][0];
    const char* Bt = (const char*)&Bsm[cur][0];

    s16x8 af[4], bf[4];
    #pragma unroll
    for (int mi = 0; mi < 4; ++mi){
      const int row = wm*64 + mi*16 + lr;
      af[mi] = *(const s16x8*)(At + row*64 + (((g + (row >> 1)) & 3) << 4));
    }
    #pragma unroll
    for (int ni = 0; ni < 4; ++ni){
      const int row = wn*64 + ni*16 + lr;
      bf[ni] = *(const s16x8*)(Bt + row*64 + (((g + (row >> 1)) & 3) << 4));
    }
    __builtin_amdgcn_s_setprio(1);
    #pragma unroll
    for (int mi = 0; mi < 4; ++mi)
      #pragma unroll
      for (int ni = 0; ni < 4; ++ni)
        acc[mi][ni] = __builtin_amdgcn_mfma_f32_16x16x32_bf16(af[mi], bf[ni], acc[mi][ni], 0, 0, 0);
    __builtin_amdgcn_s_setprio(0);

    asm volatile("s_barrier" ::: "memory");   // all waves done reading buf[cur]
    if (t + 2 < nk) stage(t + 2, cur);        // refill buf[cur] for tile t+2
  }

  // lean epilogue (R15-verified): n-decode hoisted per-ni, vT 8B stores
  #pragma unroll
  for (int ni = 0; ni < 4; ++ni){
    const int n = n0 + wn*64 + ni*16 + lr;
    const float bv = bias[n];
    const int which = n >> 10;
    const int cc = n & 1023;
    const int h = cc >> 6, d = cc & 63;
    #pragma unroll
    for (int mi = 0; mi < 4; ++mi){
      const int m = m0 + wm*64 + mi*16 + g*4;          // r=0; m..m+3 share bq & t-run
      const int bq = m >> 11, t = m & 2047;
      const int bh = bq*16 + h;
      if (which == 2){
        union { unsigned int u[2]; u16x4 v; } w;
        w.u[0] = cvtpk(acc[mi][ni][0] + bv, acc[mi][ni][1] + bv);
        w.u[1] = cvtpk(acc[mi][ni][2] + bv, acc[mi][ni][3] + bv);
        *(u16x4*)&vT_ws[((size_t)bh*D_ + d)*T_ + t] = w.v;   // 8B store, r-contig
      } else {
        unsigned short* dst = (which == 0 ? q_ws : k_ws) + ((size_t)bh*T_ + t)*D_ + d;
        const float sc = (which == 0) ? 0.022542110013890054f : 1.f; // log2e/64 into q
        #pragma unroll
        for (int r = 0; r < 4; ++r) dst[(size_t)r*D_] = f2bf((acc[mi][ni][r] + bv)*sc);
      }
    }
  }
}

// ---------------- proj GEMM 128x128 (R15 kernel, MODE-1 path only) ----------------
__global__ __launch_bounds__(256, 4) void gemm_proj(
    const unsigned short* __restrict__ A, const unsigned short* __restrict__ Bw,
    const float* __restrict__ bias, int M, int N, int K, int nbx,
    float* __restrict__ out)
{
  __shared__ unsigned short Asm[2][128*32];
  __shared__ unsigned short Bsm[2][128*32];
  const int tid = threadIdx.x;
  const int lane = tid & 63, wid = tid >> 6;
  const int g = lane >> 4, lr = lane & 15;
  const int wr = wid >> 1, wc = wid & 1;
  const int nwg = (int)gridDim.x;
  const int cpx = nwg >> 3;
  const int orig = (int)blockIdx.x;
  const int wgid = (orig & 7) * cpx + (orig >> 3);
  const int bx = wgid % nbx, by = wgid / nbx;
  const int m0 = by * 128, n0 = bx * 128;

  f32x4 acc[4][4];
  #pragma unroll
  for (int i = 0; i < 4; ++i)
    #pragma unroll
    for (int j = 0; j < 4; ++j) acc[i][j] = (f32x4){0.f,0.f,0.f,0.f};

  auto stage = [&](int kt, int buf){
    #pragma unroll
    for (int j = 0; j < 2; ++j){
      const int c = j*256 + tid;
      const int row = c >> 2;
      const int srcq = ((c & 3) - (row >> 1)) & 3;
      gload_lds16((const char*)A  + ((size_t)(m0+row)*K)*2 + (size_t)kt*64 + srcq*16,
                  (char*)&Asm[buf][0] + (size_t)c*16);
      gload_lds16((const char*)Bw + ((size_t)(n0+row)*K)*2 + (size_t)kt*64 + srcq*16,
                  (char*)&Bsm[buf][0] + (size_t)c*16);
    }
  };

  const int nk = K >> 5;
  stage(0, 0);
  stage(1, 1);

  for (int t = 0; t < nk; ++t){
    const int cur = t & 1;
    if (t < nk - 1) asm volatile("s_waitcnt vmcnt(4)" ::: "memory");
    else            asm volatile("s_waitcnt vmcnt(0)" ::: "memory");
    asm volatile("s_barrier" ::: "memory");

    const char* At = (const char*)&Asm[cur][0];
    const char* Bt = (const char*)&Bsm[cur][0];

    s16x8 af[4], bf[4];
    #pragma unroll
    for (int mi = 0; mi < 4; ++mi){
      const int row = wr*64 + mi*16 + lr;
      af[mi] = *(const s16x8*)(At + row*64 + (((g + (row >> 1)) & 3) << 4));
    }
    #pragma unroll
    for (int ni = 0; ni < 4; ++ni){
      const int row = wc*64 + ni*16 + lr;
      bf[ni] = *(const s16x8*)(Bt + row*64 + (((g + (row >> 1)) & 3) << 4));
    }
    __builtin_amdgcn_s_setprio(1);
    #pragma unroll
    for (int mi = 0; mi < 4; ++mi)
      #pragma unroll
      for (int ni = 0; ni < 4; ++ni)
        acc[mi][ni] = __builtin_amdgcn_mfma_f32_16x16x32_bf16(af[mi], bf[ni], acc[mi][ni], 0, 0, 0);
    __builtin_amdgcn_s_setprio(0);

    asm volatile("s_barrier" ::: "memory");
    if (t + 2 < nk) stage(t + 2, cur);
  }

  #pragma unroll
  for (int mi = 0; mi < 4; ++mi){
    #pragma unroll
    for (int ni = 0; ni < 4; ++ni){
      const int n = n0 + wc*64 + ni*16 + lr;
      const float bv = bias[n];
      #pragma unroll
      for (int r = 0; r < 4; ++r){
        const int m = m0 + wr*64 + mi*16 + g*4 + r;
        out[(size_t)m*N + n] = acc[mi][ni][r] + bv;
      }
    }
  }
}

// ---------------- flash attention v5 + T5 setprio (R15, unchanged) ----------------
__global__ __launch_bounds__(256, 4) void attn_kernel(
    const unsigned short* __restrict__ q_ws, const unsigned short* __restrict__ k_ws,
    const unsigned short* __restrict__ vT_ws, unsigned short* __restrict__ y_ws)
{
  __shared__ __align__(16) unsigned short Ks[2][64*64];
  __shared__ __align__(16) unsigned short Vs[2][64*64];

  const int tid = threadIdx.x;
  const int lane = tid & 63, wid = tid >> 6;
  const int g = lane >> 4, lr = lane & 15;
  const int orig = (int)blockIdx.x;
  const int wgid = (orig & 7) * 128 + (orig >> 3);
  const int p  = wgid & 15;
  const int bh = wgid >> 4;
  const int qwA = p*64 + wid*16,  qwB = (31 - p)*64 + wid*16;
  const int qrowA = qwA + lr,     qrowB = qwB + lr;
  const int swz = (lr & 7) << 4;

  const unsigned short* Qb = q_ws  + (size_t)bh*T_*D_;
  const unsigned short* Kb = k_ws  + (size_t)bh*T_*D_;
  const unsigned short* Vb = vT_ws + (size_t)bh*D_*T_;

  auto stage = [&](int t, int buf){
    const int kt0 = t << 6;
    #pragma unroll
    for (int s = 0; s < 2; ++s){
      const int c = s*256 + tid;
      const int r = c >> 3;
      const int scol = ((c & 7) << 4) ^ ((r & 7) << 4);
      gload_lds16((const char*)Kb + ((size_t)(kt0 + r)*D_)*2 + scol,
                  (char*)&Ks[buf][0] + c*16);
      gload_lds16((const char*)Vb + ((size_t)r*T_ + kt0)*2 + scol,
                  (char*)&Vs[buf][0] + c*16);
    }
  };

  const s16x8 bqA0 = *(const s16x8*)&Qb[(size_t)(qwA+lr)*D_ + g*8];
  const s16x8 bqA1 = *(const s16x8*)&Qb[(size_t)(qwA+lr)*D_ + 32 + g*8];
  const s16x8 bqB0 = *(const s16x8*)&Qb[(size_t)(qwB+lr)*D_ + g*8];
  const s16x8 bqB1 = *(const s16x8*)&Qb[(size_t)(qwB+lr)*D_ + 32 + g*8];

  s16x8 ones;
  #pragma unroll
  for (int j = 0; j < 8; ++j) ones[j] = (short)0x3F80;

  f32x4 yA[4], yB[4];
  #pragma unroll
  for (int dt = 0; dt < 4; ++dt){ yA[dt] = (f32x4){0.f,0.f,0.f,0.f}; yB[dt] = (f32x4){0.f,0.f,0.f,0.f}; }
  f32x4 lacA = (f32x4){0.f,0.f,0.f,0.f}, lacB = (f32x4){0.f,0.f,0.f,0.f};
  float mA = -1e30f, mB = -1e30f;

  const int ntA = p + 1, ntB = 32 - p;
  stage(0, 0);
  __syncthreads();

  for (int t = 0; t < ntB; ++t){
    const int cur = t & 1;
    if (t + 1 < ntB) stage(t + 1, cur ^ 1);
    const int kt0 = t << 6;
    const unsigned short* Kt = &Ks[cur][0];
    const unsigned short* Vt = &Vs[cur][0];
    unsigned short* Pw = &Ks[cur][wid*1024];
    const bool actA = (t < ntA);

    f32x4 sB[4], sA[4];
    __builtin_amdgcn_s_setprio(1);
    #pragma unroll
    for (int kk = 0; kk < 4; ++kk){
      const int row = kk*16 + lr;
      const s16x8 a0 = *(const s16x8*)&Kt[row*64 + (((g*16)      ^ swz) >> 1)];
      const s16x8 a1 = *(const s16x8*)&Kt[row*64 + (((64 + g*16) ^ swz) >> 1)];
      f32x4 acc = (f32x4){0.f,0.f,0.f,0.f};
      acc = __builtin_amdgcn_mfma_f32_16x16x32_bf16(a0, bqB0, acc, 0, 0, 0);
      acc = __builtin_amdgcn_mfma_f32_16x16x32_bf16(a1, bqB1, acc, 0, 0, 0);
      sB[kk] = acc;
      if (actA){
        f32x4 acc2 = (f32x4){0.f,0.f,0.f,0.f};
        acc2 = __builtin_amdgcn_mfma_f32_16x16x32_bf16(a0, bqA0, acc2, 0, 0, 0);
        acc2 = __builtin_amdgcn_mfma_f32_16x16x32_bf16(a1, bqA1, acc2, 0, 0, 0);
        sA[kk] = acc2;
      }
    }
    __builtin_amdgcn_s_setprio(0);

    if (kt0 + 63 > qwB){
      #pragma unroll
      for (int kk = 0; kk < 4; ++kk)
        #pragma unroll
        for (int r = 0; r < 4; ++r)
          if (kt0 + kk*16 + g*4 + r > qrowB) sB[kk][r] = -1e30f;
    }
    {
      float m01 = fmaxf(fmaxf(sB[0][0], sB[0][1]), fmaxf(sB[0][2], sB[0][3]));
      float m23 = fmaxf(fmaxf(sB[1][0], sB[1][1]), fmaxf(sB[1][2], sB[1][3]));
      float m45 = fmaxf(fmaxf(sB[2][0], sB[2][1]), fmaxf(sB[2][2], sB[2][3]));
      float m67 = fmaxf(fmaxf(sB[3][0], sB[3][1]), fmaxf(sB[3][2], sB[3][3]));
      float mx = fmaxf(fmaxf(m01, m23), fmaxf(m45, m67));
      mx = fmaxf(mx, __shfl_xor(mx, 16, 64));
      mx = fmaxf(mx, __shfl_xor(mx, 32, 64));
      if (!__all(mx <= mB + 8.f)){
        const float mnew = fmaxf(mB, mx);
        const float corr = exp2_asm(mB - mnew);
        mB = mnew;
        lacB[0] *= corr;
        #pragma unroll
        for (int dt = 0; dt < 4; ++dt)
          #pragma unroll
          for (int r = 0; r < 4; ++r) yB[dt][r] *= corr;
      }
    }
    union { unsigned int u[2]; u16x4 v; } pkB[4];
    #pragma unroll
    for (int kk = 0; kk < 4; ++kk){
      const float e0 = exp2_asm(sB[kk][0] - mB);
      const float e1 = exp2_asm(sB[kk][1] - mB);
      const float e2 = exp2_asm(sB[kk][2] - mB);
      const float e3 = exp2_asm(sB[kk][3] - mB);
      pkB[kk].u[0] = cvtpk(e0, e1);
      pkB[kk].u[1] = cvtpk(e2, e3);
    }

    asm volatile("s_barrier" ::: "memory");

    #pragma unroll
    for (int kk = 0; kk < 4; ++kk)
      *(u16x4*)&Pw[lr*64 + (((kk*32 + g*8) ^ swz) >> 1)] = pkB[kk].v;
    asm volatile("" ::: "memory");
    {
      const s16x8 p0 = *(const s16x8*)&Pw[lr*64 + (((g*16)      ^ swz) >> 1)];
      const s16x8 p1 = *(const s16x8*)&Pw[lr*64 + (((64 + g*16) ^ swz) >> 1)];
      __builtin_amdgcn_s_setprio(1);
      lacB = __builtin_amdgcn_mfma_f32_16x16x32_bf16(ones, p0, lacB, 0, 0, 0);
      lacB = __builtin_amdgcn_mfma_f32_16x16x32_bf16(ones, p1, lacB, 0, 0, 0);
      #pragma unroll
      for (int dt = 0; dt < 4; ++dt){
        const int vrow = dt*16 + lr;
        const s16x8 v0 = *(const s16x8*)&Vt[vrow*64 + (((g*16)      ^ swz) >> 1)];
        const s16x8 v1 = *(const s16x8*)&Vt[vrow*64 + (((64 + g*16) ^ swz) >> 1)];
        yB[dt] = __builtin_amdgcn_mfma_f32_16x16x32_bf16(v0, p0, yB[dt], 0, 0, 0);
        yB[dt] = __builtin_amdgcn_mfma_f32_16x16x32_bf16(v1, p1, yB[dt], 0, 0, 0);
      }
      __builtin_amdgcn_s_setprio(0);
    }

    if (actA){
      if (kt0 + 63 > qwA){
        #pragma unroll
        for (int kk = 0; kk < 4; ++kk)
          #pragma unroll
          for (int r = 0; r < 4; ++r)
            if (kt0 + kk*16 + g*4 + r > qrowA) sA[kk][r] = -1e30f;
      }
      float m01 = fmaxf(fmaxf(sA[0][0], sA[0][1]), fmaxf(sA[0][2], sA[0][3]));
      float m23 = fmaxf(fmaxf(sA[1][0], sA[1][1]), fmaxf(sA[1][2], sA[1][3]));
      float m45 = fmaxf(fmaxf(sA[2][0], sA[2][1]), fmaxf(sA[2][2], sA[2][3]));
      float m67 = fmaxf(fmaxf(sA[3][0], sA[3][1]), fmaxf(sA[3][2], sA[3][3]));
      float mx = fmaxf(fmaxf(m01, m23), fmaxf(m45, m67));
      mx = fmaxf(mx, __shfl_xor(mx, 16, 64));
      mx = fmaxf(mx, __shfl_xor(mx, 32, 64));
      if (!__all(mx <= mA + 8.f)){
        const float mnew = fmaxf(mA, mx);
        const float corr = exp2_asm(mA - mnew);
        mA = mnew;
        lacA[0] *= corr;
        #pragma unroll
        for (int dt = 0; dt < 4; ++dt)
          #pragma unroll
          for (int r = 0; r < 4; ++r) yA[dt][r] *= corr;
      }
      union { unsigned int u[2]; u16x4 v; } pkA[4];
      #pragma unroll
      for (int kk = 0; kk < 4; ++kk){
        const float e0 = exp2_asm(sA[kk][0] - mA);
        const float e1 = exp2_asm(sA[kk][1] - mA);
        const float e2 = exp2_asm(sA[kk][2] - mA);
        const float e3 = exp2_asm(sA[kk][3] - mA);
        pkA[kk].u[0] = cvtpk(e0, e1);
        pkA[kk].u[1] = cvtpk(e2, e3);
      }
      asm volatile("" ::: "memory");
      #pragma unroll
      for (int kk = 0; kk < 4; ++kk)
        *(u16x4*)&Pw[lr*64 + (((kk*32 + g*8) ^ swz) >> 1)] = pkA[kk].v;
      asm volatile("" ::: "memory");
      const s16x8 p0 = *(const s16x8*)&Pw[lr*64 + (((g*16)      ^ swz) >> 1)];
      const s16x8 p1 = *(const s16x8*)&Pw[lr*64 + (((64 + g*16) ^ swz) >> 1)];
      __builtin_amdgcn_s_setprio(1);
      lacA = __builtin_amdgcn_mfma_f32_16x16x32_bf16(ones, p0, lacA, 0, 0, 0);
      lacA = __builtin_amdgcn_mfma_f32_16x16x32_bf16(ones, p1, lacA, 0, 0, 0);
      #pragma unroll
      for (int dt = 0; dt < 4; ++dt){
        const int vrow = dt*16 + lr;
        const s16x8 v0 = *(const s16x8*)&Vt[vrow*64 + (((g*16)      ^ swz) >> 1)];
        const s16x8 v1 = *(const s16x8*)&Vt[vrow*64 + (((64 + g*16) ^ swz) >> 1)];
        yA[dt] = __builtin_amdgcn_mfma_f32_16x16x32_bf16(v0, p0, yA[dt], 0, 0, 0);
        yA[dt] = __builtin_amdgcn_mfma_f32_16x16x32_bf16(v1, p1, yA[dt], 0, 0, 0);
      }
      __builtin_amdgcn_s_setprio(0);
    }

    __syncthreads();
  }

  const int bq = bh >> 4, h = bh & 15;
  {
    const float inv = 1.f / lacB[0];
    #pragma unroll
    for (int dt = 0; dt < 4; ++dt){
      union { unsigned int u[2]; u16x4 v; } w;
      w.u[0] = cvtpk(yB[dt][0]*inv, yB[dt][1]*inv);
      w.u[1] = cvtpk(yB[dt][2]*inv, yB[dt][3]*inv);
      *(u16x4*)&y_ws[((size_t)(bq*T_ + qwB + lr))*C_ + h*64 + dt*16 + g*4] = w.v;
    }
  }
  {
    const float inv = 1.f / lacA[0];
    #pragma unroll
    for (int dt = 0; dt < 4; ++dt){
      union { unsigned int u[2]; u16x4 v; } w;
      w.u[0] = cvtpk(yA[dt][0]*inv, yA[dt][1]*inv);
      w.u[1] = cvtpk(yA[dt][2]*inv, yA[dt][3]*inv);
      *(u16x4*)&y_ws[((size_t)(bq*T_ + qwA + lr))*C_ + h*64 + dt*16 + g*4] = w.v;
    }
  }
}

extern "C" void kernel_launch(void* const* d_in, const int* in_sizes, int n_in,
                              void* d_out, int out_size, void* d_ws, size_t ws_size,
                              hipStream_t stream) {
  const float* x  = (const float*)d_in[0];
  const float* Wa = (const float*)d_in[1];
  const float* ba = (const float*)d_in[2];
  const float* Wp = (const float*)d_in[3];
  const float* bp = (const float*)d_in[4];
  float* out = (float*)d_out;

  char* ws = (char*)d_ws;
  const size_t MB = 1024u*1024u;
  unsigned short* xb  = (unsigned short*)(ws + 0);       // 16 MiB  [8192][1024] bf16
  unsigned short* wab = (unsigned short*)(ws + 16*MB);   //  6 MiB  [3072][1024]
  unsigned short* wpb = (unsigned short*)(ws + 22*MB);   //  2 MiB  [1024][1024]
  unsigned short* qws = (unsigned short*)(ws + 24*MB);   // 16 MiB  [64][2048][64]
  unsigned short* kws = (unsigned short*)(ws + 40*MB);   // 16 MiB  [64][2048][64]
  unsigned short* vT  = (unsigned short*)(ws + 56*MB);   // 16 MiB  [64][64][2048]
  unsigned short* yws = (unsigned short*)(ws + 72*MB);   // 16 MiB  [8192][1024]

  cvt3_kernel<<<6144, 256, 0, stream>>>(x, xb, Wa, wab, Wp, wpb);

  // QKV: M=8192 (32 tiles of 256), N=3072 (24 tiles of 128) -> 768 = 3/CU exact
  gemm_qkv<<<dim3(768), 512, 0, stream>>>(xb, wab, ba, 8192, 3072, 1024, 24,
                                          qws, kws, vT);
  attn_kernel<<<dim3(1024), 256, 0, stream>>>(qws, kws, vT, yws);
  // proj: M=8192, N=1024 (8 tiles) -> 512 blocks = 2/CU, single round
  gemm_proj<<<dim3(512), 256, 0, stream>>>(yws, wpb, bp, 8192, 1024, 1024, 8, out);
}

// Round 17
// 179.287 us; speedup vs baseline: 3.2624x; 3.2624x over previous
//
#include <hip/hip_runtime.h>

typedef __attribute__((ext_vector_type(8))) short s16x8;
typedef __attribute__((ext_vector_type(4))) float f32x4;
typedef __attribute__((ext_vector_type(4))) unsigned short u16x4;

#define T_  2048
#define C_  1024
#define D_  64

__device__ __forceinline__ unsigned short f2bf(float f){
  union { float fv; unsigned int u; } v; v.fv = f;
  unsigned int r = v.u + 0x7FFFu + ((v.u >> 16) & 1u);
  return (unsigned short)(r >> 16);
}

__device__ __forceinline__ float exp2_asm(float x){
  float r; asm("v_exp_f32 %0, %1" : "=v"(r) : "v"(x)); return r;
}
__device__ __forceinline__ unsigned int cvtpk(float lo, float hi){
  unsigned int r; asm("v_cvt_pk_bf16_f32 %0, %1, %2" : "=v"(r) : "v"(lo), "v"(hi)); return r;
}

__device__ __forceinline__ void gload_lds16(const void* g, void* l){
  __builtin_amdgcn_global_load_lds(
      (const __attribute__((address_space(1))) unsigned int*)g,
      (__attribute__((address_space(3))) unsigned int*)l, 16, 0, 0);
}

// ---------------- fused fp32 -> bf16 convert (x, W_attn, W_proj in one launch) ----------------
__global__ __launch_bounds__(256) void cvt3_kernel(
    const float* __restrict__ x,  unsigned short* __restrict__ xb,
    const float* __restrict__ wa, unsigned short* __restrict__ wab,
    const float* __restrict__ wp, unsigned short* __restrict__ wpb){
  const int b = blockIdx.x;
  const float* s; unsigned short* d; size_t base;
  if (b < 4096)      { s = x;  d = xb;  base = (size_t)b * 2048u; }
  else if (b < 5632) { s = wa; d = wab; base = (size_t)(b - 4096) * 2048u; }
  else               { s = wp; d = wpb; base = (size_t)(b - 5632) * 2048u; }
  const size_t i = base + (size_t)threadIdx.x * 8u;
  f32x4 a = *(const f32x4*)(s + i);
  f32x4 c = *(const f32x4*)(s + i + 4);
  s16x8 o;
  #pragma unroll
  for (int j = 0; j < 4; ++j){ o[j] = (short)f2bf(a[j]); o[4+j] = (short)f2bf(c[j]); }
  *(s16x8*)(d + i) = o;
}

// ---------------- QKV GEMM 256x128, BK=32: tail-free grid (768 = 3/CU via LDS) ----------------
// R16 bug: __launch_bounds__(512,6) clamped VGPR to 40 -> accumulator spilled
// to scratch (FETCH 863MB, MfmaUtil 0.7%).  Fix: (512,4) -- VGPR cap 512, no
// pressure; 48KB LDS alone enforces 3 blocks/CU (24 waves = 6/SIMD).
// Everything else identical: per-wave body = 16 MFMA + 8 ds_read_b128,
// counted vmcnt(3) head, stage(t+2) tail, 0-conflict swizzle, lean epilogue.
__global__ __launch_bounds__(512, 4) void gemm_qkv(
    const unsigned short* __restrict__ A, const unsigned short* __restrict__ Bw,
    const float* __restrict__ bias, int M, int N, int K, int nbx,
    unsigned short* __restrict__ q_ws, unsigned short* __restrict__ k_ws,
    unsigned short* __restrict__ vT_ws)
{
  __shared__ unsigned short Asm[2][256*32];   // 16 KB x2
  __shared__ unsigned short Bsm[2][128*32];   //  8 KB x2  (48 KB total -> 3 blocks/CU)
  const int tid = threadIdx.x;
  const int lane = tid & 63, wid = tid >> 6;
  const int g = lane >> 4, lr = lane & 15;
  const int wm = wid >> 1, wn = wid & 1;      // 4M x 2N, wave-tile 64x64
  const int nwg = (int)gridDim.x;
  const int cpx = nwg >> 3;
  const int orig = (int)blockIdx.x;
  const int wgid = (orig & 7) * cpx + (orig >> 3);   // XCD-chunked (nwg % 8 == 0)
  const int bx = wgid % nbx, by = wgid / nbx;
  const int m0 = by * 256, n0 = bx * 128;

  f32x4 acc[4][4];
  #pragma unroll
  for (int i = 0; i < 4; ++i)
    #pragma unroll
    for (int j = 0; j < 4; ++j) acc[i][j] = (f32x4){0.f,0.f,0.f,0.f};

  // stage one BK=32 tile: A 1024 chunks + B 512 chunks = 3 loads/thread
  auto stage = [&](int kt, int buf){
    #pragma unroll
    for (int j = 0; j < 2; ++j){
      const int c = j*512 + tid;              // A: 1024 chunks = 256 rows x 4
      const int row = c >> 2;
      const int srcq = ((c & 3) - (row >> 1)) & 3;
      gload_lds16((const char*)A + ((size_t)(m0+row)*K)*2 + (size_t)kt*64 + srcq*16,
                  (char*)&Asm[buf][0] + (size_t)c*16);
    }
    {
      const int c = tid;                      // B: 512 chunks = 128 rows x 4
      const int row = c >> 2;
      const int srcq = ((c & 3) - (row >> 1)) & 3;
      gload_lds16((const char*)Bw + ((size_t)(n0+row)*K)*2 + (size_t)kt*64 + srcq*16,
                  (char*)&Bsm[buf][0] + (size_t)c*16);
    }
  };

  const int nk = K >> 5;                      // 32 K-tiles
  stage(0, 0);
  stage(1, 1);                                // 6 outstanding

  for (int t = 0; t < nk; ++t){
    const int cur = t & 1;
    if (t < nk - 1) asm volatile("s_waitcnt vmcnt(3)" ::: "memory");  // tile t landed
    else            asm volatile("s_waitcnt vmcnt(0)" ::: "memory");
    asm volatile("s_barrier" ::: "memory");

    const char* At = (const char*)&Asm[cur][0];
    const char* Bt = (const char*)&Bsm[cur][0];

    s16x8 af[4], bf[4];
    #pragma unroll
    for (int mi = 0; mi < 4; ++mi){
      const int row = wm*64 + mi*16 + lr;
      af[mi] = *(const s16x8*)(At + row*64 + (((g + (row >> 1)) & 3) << 4));
    }
    #pragma unroll
    for (int ni = 0; ni < 4; ++ni){
      const int row = wn*64 + ni*16 + lr;
      bf[ni] = *(const s16x8*)(Bt + row*64 + (((g + (row >> 1)) & 3) << 4));
    }
    __builtin_amdgcn_s_setprio(1);
    #pragma unroll
    for (int mi = 0; mi < 4; ++mi)
      #pragma unroll
      for (int ni = 0; ni < 4; ++ni)
        acc[mi][ni] = __builtin_amdgcn_mfma_f32_16x16x32_bf16(af[mi], bf[ni], acc[mi][ni], 0, 0, 0);
    __builtin_amdgcn_s_setprio(0);

    asm volatile("s_barrier" ::: "memory");   // all waves done reading buf[cur]
    if (t + 2 < nk) stage(t + 2, cur);        // refill buf[cur] for tile t+2
  }

  // lean epilogue (R15-verified): n-decode hoisted per-ni, vT 8B stores
  #pragma unroll
  for (int ni = 0; ni < 4; ++ni){
    const int n = n0 + wn*64 + ni*16 + lr;
    const float bv = bias[n];
    const int which = n >> 10;
    const int cc = n & 1023;
    const int h = cc >> 6, d = cc & 63;
    #pragma unroll
    for (int mi = 0; mi < 4; ++mi){
      const int m = m0 + wm*64 + mi*16 + g*4;          // r=0; m..m+3 share bq & t-run
      const int bq = m >> 11, t = m & 2047;
      const int bh = bq*16 + h;
      if (which == 2){
        union { unsigned int u[2]; u16x4 v; } w;
        w.u[0] = cvtpk(acc[mi][ni][0] + bv, acc[mi][ni][1] + bv);
        w.u[1] = cvtpk(acc[mi][ni][2] + bv, acc[mi][ni][3] + bv);
        *(u16x4*)&vT_ws[((size_t)bh*D_ + d)*T_ + t] = w.v;   // 8B store, r-contig
      } else {
        unsigned short* dst = (which == 0 ? q_ws : k_ws) + ((size_t)bh*T_ + t)*D_ + d;
        const float sc = (which == 0) ? 0.022542110013890054f : 1.f; // log2e/64 into q
        #pragma unroll
        for (int r = 0; r < 4; ++r) dst[(size_t)r*D_] = f2bf((acc[mi][ni][r] + bv)*sc);
      }
    }
  }
}

// ---------------- proj GEMM 128x128 (R15 kernel, MODE-1 path only) ----------------
__global__ __launch_bounds__(256, 4) void gemm_proj(
    const unsigned short* __restrict__ A, const unsigned short* __restrict__ Bw,
    const float* __restrict__ bias, int M, int N, int K, int nbx,
    float* __restrict__ out)
{
  __shared__ unsigned short Asm[2][128*32];
  __shared__ unsigned short Bsm[2][128*32];
  const int tid = threadIdx.x;
  const int lane = tid & 63, wid = tid >> 6;
  const int g = lane >> 4, lr = lane & 15;
  const int wr = wid >> 1, wc = wid & 1;
  const int nwg = (int)gridDim.x;
  const int cpx = nwg >> 3;
  const int orig = (int)blockIdx.x;
  const int wgid = (orig & 7) * cpx + (orig >> 3);
  const int bx = wgid % nbx, by = wgid / nbx;
  const int m0 = by * 128, n0 = bx * 128;

  f32x4 acc[4][4];
  #pragma unroll
  for (int i = 0; i < 4; ++i)
    #pragma unroll
    for (int j = 0; j < 4; ++j) acc[i][j] = (f32x4){0.f,0.f,0.f,0.f};

  auto stage = [&](int kt, int buf){
    #pragma unroll
    for (int j = 0; j < 2; ++j){
      const int c = j*256 + tid;
      const int row = c >> 2;
      const int srcq = ((c & 3) - (row >> 1)) & 3;
      gload_lds16((const char*)A  + ((size_t)(m0+row)*K)*2 + (size_t)kt*64 + srcq*16,
                  (char*)&Asm[buf][0] + (size_t)c*16);
      gload_lds16((const char*)Bw + ((size_t)(n0+row)*K)*2 + (size_t)kt*64 + srcq*16,
                  (char*)&Bsm[buf][0] + (size_t)c*16);
    }
  };

  const int nk = K >> 5;
  stage(0, 0);
  stage(1, 1);

  for (int t = 0; t < nk; ++t){
    const int cur = t & 1;
    if (t < nk - 1) asm volatile("s_waitcnt vmcnt(4)" ::: "memory");
    else            asm volatile("s_waitcnt vmcnt(0)" ::: "memory");
    asm volatile("s_barrier" ::: "memory");

    const char* At = (const char*)&Asm[cur][0];
    const char* Bt = (const char*)&Bsm[cur][0];

    s16x8 af[4], bf[4];
    #pragma unroll
    for (int mi = 0; mi < 4; ++mi){
      const int row = wr*64 + mi*16 + lr;
      af[mi] = *(const s16x8*)(At + row*64 + (((g + (row >> 1)) & 3) << 4));
    }
    #pragma unroll
    for (int ni = 0; ni < 4; ++ni){
      const int row = wc*64 + ni*16 + lr;
      bf[ni] = *(const s16x8*)(Bt + row*64 + (((g + (row >> 1)) & 3) << 4));
    }
    __builtin_amdgcn_s_setprio(1);
    #pragma unroll
    for (int mi = 0; mi < 4; ++mi)
      #pragma unroll
      for (int ni = 0; ni < 4; ++ni)
        acc[mi][ni] = __builtin_amdgcn_mfma_f32_16x16x32_bf16(af[mi], bf[ni], acc[mi][ni], 0, 0, 0);
    __builtin_amdgcn_s_setprio(0);

    asm volatile("s_barrier" ::: "memory");
    if (t + 2 < nk) stage(t + 2, cur);
  }

  #pragma unroll
  for (int mi = 0; mi < 4; ++mi){
    #pragma unroll
    for (int ni = 0; ni < 4; ++ni){
      const int n = n0 + wc*64 + ni*16 + lr;
      const float bv = bias[n];
      #pragma unroll
      for (int r = 0; r < 4; ++r){
        const int m = m0 + wr*64 + mi*16 + g*4 + r;
        out[(size_t)m*N + n] = acc[mi][ni][r] + bv;
      }
    }
  }
}

// ---------------- flash attention v5 + T5 setprio (R15, unchanged) ----------------
__global__ __launch_bounds__(256, 4) void attn_kernel(
    const unsigned short* __restrict__ q_ws, const unsigned short* __restrict__ k_ws,
    const unsigned short* __restrict__ vT_ws, unsigned short* __restrict__ y_ws)
{
  __shared__ __align__(16) unsigned short Ks[2][64*64];
  __shared__ __align__(16) unsigned short Vs[2][64*64];

  const int tid = threadIdx.x;
  const int lane = tid & 63, wid = tid >> 6;
  const int g = lane >> 4, lr = lane & 15;
  const int orig = (int)blockIdx.x;
  const int wgid = (orig & 7) * 128 + (orig >> 3);
  const int p  = wgid & 15;
  const int bh = wgid >> 4;
  const int qwA = p*64 + wid*16,  qwB = (31 - p)*64 + wid*16;
  const int qrowA = qwA + lr,     qrowB = qwB + lr;
  const int swz = (lr & 7) << 4;

  const unsigned short* Qb = q_ws  + (size_t)bh*T_*D_;
  const unsigned short* Kb = k_ws  + (size_t)bh*T_*D_;
  const unsigned short* Vb = vT_ws + (size_t)bh*D_*T_;

  auto stage = [&](int t, int buf){
    const int kt0 = t << 6;
    #pragma unroll
    for (int s = 0; s < 2; ++s){
      const int c = s*256 + tid;
      const int r = c >> 3;
      const int scol = ((c & 7) << 4) ^ ((r & 7) << 4);
      gload_lds16((const char*)Kb + ((size_t)(kt0 + r)*D_)*2 + scol,
                  (char*)&Ks[buf][0] + c*16);
      gload_lds16((const char*)Vb + ((size_t)r*T_ + kt0)*2 + scol,
                  (char*)&Vs[buf][0] + c*16);
    }
  };

  const s16x8 bqA0 = *(const s16x8*)&Qb[(size_t)(qwA+lr)*D_ + g*8];
  const s16x8 bqA1 = *(const s16x8*)&Qb[(size_t)(qwA+lr)*D_ + 32 + g*8];
  const s16x8 bqB0 = *(const s16x8*)&Qb[(size_t)(qwB+lr)*D_ + g*8];
  const s16x8 bqB1 = *(const s16x8*)&Qb[(size_t)(qwB+lr)*D_ + 32 + g*8];

  s16x8 ones;
  #pragma unroll
  for (int j = 0; j < 8; ++j) ones[j] = (short)0x3F80;

  f32x4 yA[4], yB[4];
  #pragma unroll
  for (int dt = 0; dt < 4; ++dt){ yA[dt] = (f32x4){0.f,0.f,0.f,0.f}; yB[dt] = (f32x4){0.f,0.f,0.f,0.f}; }
  f32x4 lacA = (f32x4){0.f,0.f,0.f,0.f}, lacB = (f32x4){0.f,0.f,0.f,0.f};
  float mA = -1e30f, mB = -1e30f;

  const int ntA = p + 1, ntB = 32 - p;
  stage(0, 0);
  __syncthreads();

  for (int t = 0; t < ntB; ++t){
    const int cur = t & 1;
    if (t + 1 < ntB) stage(t + 1, cur ^ 1);
    const int kt0 = t << 6;
    const unsigned short* Kt = &Ks[cur][0];
    const unsigned short* Vt = &Vs[cur][0];
    unsigned short* Pw = &Ks[cur][wid*1024];
    const bool actA = (t < ntA);

    f32x4 sB[4], sA[4];
    __builtin_amdgcn_s_setprio(1);
    #pragma unroll
    for (int kk = 0; kk < 4; ++kk){
      const int row = kk*16 + lr;
      const s16x8 a0 = *(const s16x8*)&Kt[row*64 + (((g*16)      ^ swz) >> 1)];
      const s16x8 a1 = *(const s16x8*)&Kt[row*64 + (((64 + g*16) ^ swz) >> 1)];
      f32x4 acc = (f32x4){0.f,0.f,0.f,0.f};
      acc = __builtin_amdgcn_mfma_f32_16x16x32_bf16(a0, bqB0, acc, 0, 0, 0);
      acc = __builtin_amdgcn_mfma_f32_16x16x32_bf16(a1, bqB1, acc, 0, 0, 0);
      sB[kk] = acc;
      if (actA){
        f32x4 acc2 = (f32x4){0.f,0.f,0.f,0.f};
        acc2 = __builtin_amdgcn_mfma_f32_16x16x32_bf16(a0, bqA0, acc2, 0, 0, 0);
        acc2 = __builtin_amdgcn_mfma_f32_16x16x32_bf16(a1, bqA1, acc2, 0, 0, 0);
        sA[kk] = acc2;
      }
    }
    __builtin_amdgcn_s_setprio(0);

    if (kt0 + 63 > qwB){
      #pragma unroll
      for (int kk = 0; kk < 4; ++kk)
        #pragma unroll
        for (int r = 0; r < 4; ++r)
          if (kt0 + kk*16 + g*4 + r > qrowB) sB[kk][r] = -1e30f;
    }
    {
      float m01 = fmaxf(fmaxf(sB[0][0], sB[0][1]), fmaxf(sB[0][2], sB[0][3]));
      float m23 = fmaxf(fmaxf(sB[1][0], sB[1][1]), fmaxf(sB[1][2], sB[1][3]));
      float m45 = fmaxf(fmaxf(sB[2][0], sB[2][1]), fmaxf(sB[2][2], sB[2][3]));
      float m67 = fmaxf(fmaxf(sB[3][0], sB[3][1]), fmaxf(sB[3][2], sB[3][3]));
      float mx = fmaxf(fmaxf(m01, m23), fmaxf(m45, m67));
      mx = fmaxf(mx, __shfl_xor(mx, 16, 64));
      mx = fmaxf(mx, __shfl_xor(mx, 32, 64));
      if (!__all(mx <= mB + 8.f)){
        const float mnew = fmaxf(mB, mx);
        const float corr = exp2_asm(mB - mnew);
        mB = mnew;
        lacB[0] *= corr;
        #pragma unroll
        for (int dt = 0; dt < 4; ++dt)
          #pragma unroll
          for (int r = 0; r < 4; ++r) yB[dt][r] *= corr;
      }
    }
    union { unsigned int u[2]; u16x4 v; } pkB[4];
    #pragma unroll
    for (int kk = 0; kk < 4; ++kk){
      const float e0 = exp2_asm(sB[kk][0] - mB);
      const float e1 = exp2_asm(sB[kk][1] - mB);
      const float e2 = exp2_asm(sB[kk][2] - mB);
      const float e3 = exp2_asm(sB[kk][3] - mB);
      pkB[kk].u[0] = cvtpk(e0, e1);
      pkB[kk].u[1] = cvtpk(e2, e3);
    }

    asm volatile("s_barrier" ::: "memory");

    #pragma unroll
    for (int kk = 0; kk < 4; ++kk)
      *(u16x4*)&Pw[lr*64 + (((kk*32 + g*8) ^ swz) >> 1)] = pkB[kk].v;
    asm volatile("" ::: "memory");
    {
      const s16x8 p0 = *(const s16x8*)&Pw[lr*64 + (((g*16)      ^ swz) >> 1)];
      const s16x8 p1 = *(const s16x8*)&Pw[lr*64 + (((64 + g*16) ^ swz) >> 1)];
      __builtin_amdgcn_s_setprio(1);
      lacB = __builtin_amdgcn_mfma_f32_16x16x32_bf16(ones, p0, lacB, 0, 0, 0);
      lacB = __builtin_amdgcn_mfma_f32_16x16x32_bf16(ones, p1, lacB, 0, 0, 0);
      #pragma unroll
      for (int dt = 0; dt < 4; ++dt){
        const int vrow = dt*16 + lr;
        const s16x8 v0 = *(const s16x8*)&Vt[vrow*64 + (((g*16)      ^ swz) >> 1)];
        const s16x8 v1 = *(const s16x8*)&Vt[vrow*64 + (((64 + g*16) ^ swz) >> 1)];
        yB[dt] = __builtin_amdgcn_mfma_f32_16x16x32_bf16(v0, p0, yB[dt], 0, 0, 0);
        yB[dt] = __builtin_amdgcn_mfma_f32_16x16x32_bf16(v1, p1, yB[dt], 0, 0, 0);
      }
      __builtin_amdgcn_s_setprio(0);
    }

    if (actA){
      if (kt0 + 63 > qwA){
        #pragma unroll
        for (int kk = 0; kk < 4; ++kk)
          #pragma unroll
          for (int r = 0; r < 4; ++r)
            if (kt0 + kk*16 + g*4 + r > qrowA) sA[kk][r] = -1e30f;
      }
      float m01 = fmaxf(fmaxf(sA[0][0], sA[0][1]), fmaxf(sA[0][2], sA[0][3]));
      float m23 = fmaxf(fmaxf(sA[1][0], sA[1][1]), fmaxf(sA[1][2], sA[1][3]));
      float m45 = fmaxf(fmaxf(sA[2][0], sA[2][1]), fmaxf(sA[2][2], sA[2][3]));
      float m67 = fmaxf(fmaxf(sA[3][0], sA[3][1]), fmaxf(sA[3][2], sA[3][3]));
      float mx = fmaxf(fmaxf(m01, m23), fmaxf(m45, m67));
      mx = fmaxf(mx, __shfl_xor(mx, 16, 64));
      mx = fmaxf(mx, __shfl_xor(mx, 32, 64));
      if (!__all(mx <= mA + 8.f)){
        const float mnew = fmaxf(mA, mx);
        const float corr = exp2_asm(mA - mnew);
        mA = mnew;
        lacA[0] *= corr;
        #pragma unroll
        for (int dt = 0; dt < 4; ++dt)
          #pragma unroll
          for (int r = 0; r < 4; ++r) yA[dt][r] *= corr;
      }
      union { unsigned int u[2]; u16x4 v; } pkA[4];
      #pragma unroll
      for (int kk = 0; kk < 4; ++kk){
        const float e0 = exp2_asm(sA[kk][0] - mA);
        const float e1 = exp2_asm(sA[kk][1] - mA);
        const float e2 = exp2_asm(sA[kk][2] - mA);
        const float e3 = exp2_asm(sA[kk][3] - mA);
        pkA[kk].u[0] = cvtpk(e0, e1);
        pkA[kk].u[1] = cvtpk(e2, e3);
      }
      asm volatile("" ::: "memory");
      #pragma unroll
      for (int kk = 0; kk < 4; ++kk)
        *(u16x4*)&Pw[lr*64 + (((kk*32 + g*8) ^ swz) >> 1)] = pkA[kk].v;
      asm volatile("" ::: "memory");
      const s16x8 p0 = *(const s16x8*)&Pw[lr*64 + (((g*16)      ^ swz) >> 1)];
      const s16x8 p1 = *(const s16x8*)&Pw[lr*64 + (((64 + g*16) ^ swz) >> 1)];
      __builtin_amdgcn_s_setprio(1);
      lacA = __builtin_amdgcn_mfma_f32_16x16x32_bf16(ones, p0, lacA, 0, 0, 0);
      lacA = __builtin_amdgcn_mfma_f32_16x16x32_bf16(ones, p1, lacA, 0, 0, 0);
      #pragma unroll
      for (int dt = 0; dt < 4; ++dt){
        const int vrow = dt*16 + lr;
        const s16x8 v0 = *(const s16x8*)&Vt[vrow*64 + (((g*16)      ^ swz) >> 1)];
        const s16x8 v1 = *(const s16x8*)&Vt[vrow*64 + (((64 + g*16) ^ swz) >> 1)];
        yA[dt] = __builtin_amdgcn_mfma_f32_16x16x32_bf16(v0, p0, yA[dt], 0, 0, 0);
        yA[dt] = __builtin_amdgcn_mfma_f32_16x16x32_bf16(v1, p1, yA[dt], 0, 0, 0);
      }
      __builtin_amdgcn_s_setprio(0);
    }

    __syncthreads();
  }

  const int bq = bh >> 4, h = bh & 15;
  {
    const float inv = 1.f / lacB[0];
    #pragma unroll
    for (int dt = 0; dt < 4; ++dt){
      union { unsigned int u[2]; u16x4 v; } w;
      w.u[0] = cvtpk(yB[dt][0]*inv, yB[dt][1]*inv);
      w.u[1] = cvtpk(yB[dt][2]*inv, yB[dt][3]*inv);
      *(u16x4*)&y_ws[((size_t)(bq*T_ + qwB + lr))*C_ + h*64 + dt*16 + g*4] = w.v;
    }
  }
  {
    const float inv = 1.f / lacA[0];
    #pragma unroll
    for (int dt = 0; dt < 4; ++dt){
      union { unsigned int u[2]; u16x4 v; } w;
      w.u[0] = cvtpk(yA[dt][0]*inv, yA[dt][1]*inv);
      w.u[1] = cvtpk(yA[dt][2]*inv, yA[dt][3]*inv);
      *(u16x4*)&y_ws[((size_t)(bq*T_ + qwA + lr))*C_ + h*64 + dt*16 + g*4] = w.v;
    }
  }
}

extern "C" void kernel_launch(void* const* d_in, const int* in_sizes, int n_in,
                              void* d_out, int out_size, void* d_ws, size_t ws_size,
                              hipStream_t stream) {
  const float* x  = (const float*)d_in[0];
  const float* Wa = (const float*)d_in[1];
  const float* ba = (const float*)d_in[2];
  const float* Wp = (const float*)d_in[3];
  const float* bp = (const float*)d_in[4];
  float* out = (float*)d_out;

  char* ws = (char*)d_ws;
  const size_t MB = 1024u*1024u;
  unsigned short* xb  = (unsigned short*)(ws + 0);       // 16 MiB  [8192][1024] bf16
  unsigned short* wab = (unsigned short*)(ws + 16*MB);   //  6 MiB  [3072][1024]
  unsigned short* wpb = (unsigned short*)(ws + 22*MB);   //  2 MiB  [1024][1024]
  unsigned short* qws = (unsigned short*)(ws + 24*MB);   // 16 MiB  [64][2048][64]
  unsigned short* kws = (unsigned short*)(ws + 40*MB);   // 16 MiB  [64][2048][64]
  unsigned short* vT  = (unsigned short*)(ws + 56*MB);   // 16 MiB  [64][64][2048]
  unsigned short* yws = (unsigned short*)(ws + 72*MB);   // 16 MiB  [8192][1024]

  cvt3_kernel<<<6144, 256, 0, stream>>>(x, xb, Wa, wab, Wp, wpb);

  // QKV: M=8192 (32 tiles of 256), N=3072 (24 tiles of 128) -> 768 = 3/CU via LDS
  gemm_qkv<<<dim3(768), 512, 0, stream>>>(xb, wab, ba, 8192, 3072, 1024, 24,
                                          qws, kws, vT);
  attn_kernel<<<dim3(1024), 256, 0, stream>>>(qws, kws, vT, yws);
  // proj: M=8192, N=1024 (8 tiles) -> 512 blocks = 2/CU, single round
  gemm_proj<<<dim3(512), 256, 0, stream>>>(yws, wpb, bp, 8192, 1024, 1024, 8, out);
}